// Round 9
// baseline (999.782 us; speedup 1.0000x reference)
//
#include <hip/hip_runtime.h>
#include <hip/hip_bf16.h>

typedef short short8 __attribute__((ext_vector_type(8)));
typedef float floatx4 __attribute__((ext_vector_type(4)));
typedef __hip_bfloat16 bf16;

#define HID 256
#define NL  4
#define AS1 __attribute__((address_space(1)))
#define AS3 __attribute__((address_space(3)))

__device__ __forceinline__ float b2f(bf16 v) { return __bfloat162float(v); }
__device__ __forceinline__ bf16 f2b(float v) { return __float2bfloat16(v); }
__device__ __forceinline__ float us2f(unsigned short u) {
    unsigned int x = ((unsigned int)u) << 16;
    return __uint_as_float(x);
}
__device__ __forceinline__ unsigned short f2us(float v) {
    bf16 t = __float2bfloat16(v);
    return *reinterpret_cast<unsigned short*>(&t);
}

// DPP row-rotate add: sum within each 16-lane row, 4 steps, pure VALU pipe.
template <int CTRL>
__device__ __forceinline__ float row_ror_add(float x) {
    return x + __int_as_float(__builtin_amdgcn_update_dpp(
        0, __float_as_int(x), CTRL, 0xF, 0xF, true));
}

// ---------------- fused zero-init: counts, fill (N each) + pooled (G*HID) ----------------
__global__ void zero_ws_kernel(int* __restrict__ a, int* __restrict__ b, int n,
                               float* __restrict__ p, int np) {
    int i = blockIdx.x * 256 + threadIdx.x;
    if (i < n) { a[i] = 0; b[i] = 0; }
    if (i < np) p[i] = 0.f;
}

// ---------------- embeddings; float4 loads, 4 nodes/block ----------------
__global__ __launch_bounds__(256) void node_embed_kernel(const int* __restrict__ x,
                                  const float* __restrict__ e0, const float* __restrict__ e1,
                                  const float* __restrict__ e2,
                                  bf16* __restrict__ hbf, int N) {
    const int tid = threadIdx.x;
    const int n = blockIdx.x * 4 + (tid >> 6);
    if (n >= N) return;
    const int c4 = (tid & 63) * 4;
    const int i0 = x[n * 3], i1 = x[n * 3 + 1], i2 = x[n * 3 + 2];
    const float4 a = *reinterpret_cast<const float4*>(e0 + i0 * HID + c4);
    const float4 b = *reinterpret_cast<const float4*>(e1 + i1 * HID + c4);
    const float4 c = *reinterpret_cast<const float4*>(e2 + i2 * HID + c4);
    ushort4 o;
    o.x = f2us(a.x + b.x + c.x);
    o.y = f2us(a.y + b.y + c.y);
    o.z = f2us(a.z + b.z + c.z);
    o.w = f2us(a.w + b.w + c.w);
    *reinterpret_cast<ushort4*>(hbf + (size_t)n * HID + c4) = o;
}

__global__ void ecombo_embed_kernel(const float* __restrict__ e0, const float* __restrict__ e1,
                                    float* __restrict__ ec) {
    int i = blockIdx.x, c = threadIdx.x;
    ec[i * HID + c] = e0[(i >> 2) * HID + c] + e1[(i & 3) * HID + c];
}

// merged: per-edge combo id + dst histogram (one pass over edges)
__global__ void edge_prep_kernel(const int* __restrict__ ea, const int* __restrict__ dst,
                                 int E, int* __restrict__ ecid, int* __restrict__ counts) {
    int e = blockIdx.x * 256 + threadIdx.x;
    if (e < E) {
        ecid[e] = ea[e * 2] * 4 + ea[e * 2 + 1];
        atomicAdd(&counts[dst[e]], 1);
    }
}

// ALL layers at once: blockIdx.x = l*32 + i -> ecp4[l][i][c]
__global__ void combo_proj_kernel(const float* __restrict__ ec, const float* __restrict__ We,
                                  const float* __restrict__ be, float* __restrict__ ecp4) {
    __shared__ float row[HID];
    int l = blockIdx.x >> 5, i = blockIdx.x & 31, c = threadIdx.x;
    row[c] = ec[i * HID + c];
    __syncthreads();
    const float* We_l = We + (size_t)l * 65536;
    float a = be[l * 256 + c];
    for (int k = 0; k < HID; ++k) a += row[k] * We_l[k * HID + c];
    ecp4[(size_t)l * 32 * HID + i * HID + c] = a;
}

// ---------------- CSR scan ----------------
__global__ void scan_local_kernel(const int* __restrict__ counts, int N,
                                  int* __restrict__ incl, int* __restrict__ bsum) {
    __shared__ int sd[256];
    int i = threadIdx.x;
    int idx = blockIdx.x * 256 + i;
    sd[i] = (idx < N) ? counts[idx] : 0;
    __syncthreads();
    for (int off = 1; off < 256; off <<= 1) {
        int t = (i >= off) ? sd[i - off] : 0;
        __syncthreads();
        sd[i] += t;
        __syncthreads();
    }
    if (idx < N) incl[idx] = sd[i];
    if (i == 255) bsum[blockIdx.x] = sd[255];
}

__global__ void scan_block_kernel(const int* __restrict__ bsum, int nb, int* __restrict__ boff) {
    __shared__ int sd[256];
    int i = threadIdx.x;
    sd[i] = (i < nb) ? bsum[i] : 0;
    __syncthreads();
    for (int off = 1; off < 256; off <<= 1) {
        int t = (i >= off) ? sd[i - off] : 0;
        __syncthreads();
        sd[i] += t;
        __syncthreads();
    }
    if (i < nb) boff[i] = (i == 0) ? 0 : sd[i - 1];
}

__global__ void scan_add_kernel(const int* __restrict__ incl, const int* __restrict__ boff,
                                int N, int* __restrict__ indptr) {
    int idx = blockIdx.x * 256 + threadIdx.x;
    if (idx < N) indptr[idx + 1] = incl[idx] + boff[blockIdx.x];
    if (idx == 0) indptr[0] = 0;
}

// sorted2: PRE-SCALED BYTE OFFSETS (x = src*2048 qkvs row, y = ecid*1024 ecp row). +4 pad.
__global__ void fill_sorted_kernel(const int* __restrict__ dst, const int* __restrict__ srcv,
                                   const int* __restrict__ ecid, const int* __restrict__ indptr,
                                   int E, int* __restrict__ fill, int2* __restrict__ sorted2) {
    int e = blockIdx.x * 256 + threadIdx.x;
    if (e < E) {
        int d = dst[e];
        int pos = indptr[d] + atomicAdd(&fill[d], 1);
        sorted2[pos] = make_int2(srcv[e] << 11, ecid[e] << 10);
    }
    if (e < 4) sorted2[E + e] = make_int2(0, 0);
}

// ---------------- weight packing: LDS-transposed, coalesced both sides ----------------
__global__ __launch_bounds__(256) void pack_wcat_kernel(
    const float* __restrict__ Wq, const float* __restrict__ Wk,
    const float* __restrict__ Wv, const float* __restrict__ Ws,
    bf16* __restrict__ wcatT) {
    __shared__ bf16 tile[64][65];
    const int jt = blockIdx.x;     // 0..15  (j tile of 64)
    const int kt = blockIdx.y;     // 0..3   (k tile of 64)
    const int l  = blockIdx.z;     // 0..3
    const int tid = threadIdx.x;
    const int jl = tid & 63;
    const int j = jt * 64 + jl;
    const float* W;
    int jj;
    if (j < 256)      { W = Wq; jj = j; }
    else if (j < 512) { W = Ws; jj = j - 256; }
    else {
        int g = (j - 512) >> 3, r = (j - 512) & 7;
        if (r < 4) { W = Wk; jj = 4 * g + r; }
        else       { W = Wv; jj = 4 * g + r - 4; }
    }
    const float* Wbase = W + (size_t)l * 65536 + jj + (size_t)(kt * 64) * 256;
    const int kr = tid >> 6;       // 0..3
#pragma unroll
    for (int i = 0; i < 16; ++i) {
        const int kl = kr + i * 4;
        tile[kl][jl] = f2b(Wbase[(size_t)kl * 256]);
    }
    __syncthreads();
    const int kl2 = tid & 63;
    const int jr = tid >> 6;
    bf16* out = wcatT + (size_t)l * 262144 + (size_t)(jt * 64) * 256 + kt * 64 + kl2;
#pragma unroll
    for (int i = 0; i < 16; ++i) {
        const int jl2 = jr + i * 4;
        out[(size_t)jl2 * 256] = tile[kl2][jl2];
    }
}

__global__ void pack_bias_kernel(const float* __restrict__ bq, const float* __restrict__ bk,
                                 const float* __restrict__ bv, const float* __restrict__ bs,
                                 float* __restrict__ bcat) {
    int idx = blockIdx.x * 256 + threadIdx.x;      // < 4096
    if (idx < 4096) {
        int l = idx >> 10, j = idx & 1023;
        const float* B;
        int jj;
        if (j < 256)      { B = bq; jj = j; }
        else if (j < 512) { B = bs; jj = j - 256; }
        else {
            int g = (j - 512) >> 3, r = (j - 512) & 7;
            if (r < 4) { B = bk; jj = 4 * g + r; }
            else       { B = bv; jj = 4 * g + r - 4; }
        }
        bcat[idx] = B[l * 256 + jj];
    }
}

// ---------------- register-B GEMM (R29): R28 + the missing column coverage ----------------
// R28 BUG: n0 = wave*64 covered only cols 0..255 of 1024 -> 3/4 of qkvs never written
// (absmax 1300 = attn read stale workspace). R29: grid 6272 = 1568 row-tiles x 4 col-groups;
// id = (d&7)*784 + (d>>3) keeps the 4 col-group blocks of the same rows adjacent on one XCD
// (A rows L2-served once). Per block: 32 rows x 256 cols; wave owns 64 cols; B panel in
// 128 VGPRs (static-indexed, fully unrolled); main loop has ZERO LDS and ZERO barriers.
// B total L2 reads ~800MB but B itself is 512KB (L2-resident). Epilogue: R26-proven
// double-buffered swizzled sC, uint4 full-sector stores.
__global__ __launch_bounds__(256, 2) void gemm_reg_kernel(
    const bf16* __restrict__ A, const bf16* __restrict__ BT,
    const float* __restrict__ bias, bf16* __restrict__ C, int M) {
    __shared__ __align__(16) bf16 sC[2][4][1024];   // 16 KB: [mi-buf][wave][16x64 swizzled]
    const int tid = threadIdx.x;
    const int lane = tid & 63;
    const int wave = tid >> 6;
    const int d = blockIdx.x;                        // 0..6271
    const int id = (d & 7) * 784 + (d >> 3);         // bijective XCD grouping (6272 = 8*784)
    const int cg = id & 3;                           // col group (256 cols)
    const int mrow = (id >> 2) * 32;                 // row tile
    const int n0 = cg * 256 + wave * 64;             // this wave's 64 output cols
    const int fr = lane & 15;
    const int quad = lane >> 4;

    // B panel -> registers (one-time per block)
    short8 bq[4][8];
#pragma unroll
    for (int ni = 0; ni < 4; ++ni)
#pragma unroll
        for (int kk = 0; kk < 8; ++kk)
            bq[ni][kk] = *reinterpret_cast<const short8*>(
                BT + (size_t)(n0 + ni * 16 + fr) * 256 + kk * 32 + quad * 8);
    float bias4[4];
#pragma unroll
    for (int ni = 0; ni < 4; ++ni) bias4[ni] = bias[n0 + ni * 16 + fr];

    const bf16* ap0 = A + (size_t)min(mrow + fr, M - 1) * 256 + quad * 8;
    const bf16* ap1 = A + (size_t)min(mrow + 16 + fr, M - 1) * 256 + quad * 8;

    floatx4 acc[2][4] = {};
    short8 a0 = *reinterpret_cast<const short8*>(ap0);
    short8 a1 = *reinterpret_cast<const short8*>(ap1);
#pragma unroll
    for (int kk = 0; kk < 8; ++kk) {
        short8 an = a0, bn = a1;
        if (kk < 7) {   // prefetch next k-chunk while MFMAs consume current
            an = *reinterpret_cast<const short8*>(ap0 + (kk + 1) * 32);
            bn = *reinterpret_cast<const short8*>(ap1 + (kk + 1) * 32);
        }
#pragma unroll
        for (int ni = 0; ni < 4; ++ni) {
            acc[0][ni] = __builtin_amdgcn_mfma_f32_16x16x32_bf16(a0, bq[ni][kk], acc[0][ni], 0, 0, 0);
            acc[1][ni] = __builtin_amdgcn_mfma_f32_16x16x32_bf16(a1, bq[ni][kk], acc[1][ni], 0, 0, 0);
        }
        a0 = an; a1 = bn;
    }

    // epilogue: per-wave swizzled LDS round-trip, 16B contiguous stores (full sectors)
    const int row16 = lane >> 3;
    const int c16 = lane & 7;
#pragma unroll
    for (int mi = 0; mi < 2; ++mi) {
        bf16* wb = &sC[mi][wave][0];
#pragma unroll
        for (int ni = 0; ni < 4; ++ni)
#pragma unroll
            for (int r = 0; r < 4; ++r)
                wb[(quad * 4 + r) * 64 + (((ni * 2 + (fr >> 3)) ^ (quad << 1)) << 3) + (fr & 7)] =
                    f2b(acc[mi][ni][r] + bias4[ni]);
#pragma unroll
        for (int h = 0; h < 2; ++h) {
            const int rr = row16 + h * 8;
            const int pg = c16 ^ (((rr >> 2) & 3) << 1);
            const uint4 vv = *reinterpret_cast<const uint4*>(wb + rr * 64 + (pg << 3));
            const int grow = mrow + mi * 16 + rr;
            if (grow < M)
                *reinterpret_cast<uint4*>(C + (size_t)grow * 1024 + n0 + c16 * 8) = vv;
        }
    }
}

// ---------------- fused attention: wave-per-node, pair-unrolled edge loop + DPP reduce ----------------
__global__ __launch_bounds__(256) void attn_node_kernel(
    const bf16* __restrict__ qkvs,     // [N,1024] q | skip | kv-interleaved
    const float* __restrict__ ecp,     // [32,256] this layer
    const int* __restrict__ indptr, const int2* __restrict__ sorted2,
    const float* __restrict__ Wbeta_l, const float* __restrict__ lng, const float* __restrict__ lnb,
    bf16* __restrict__ hbf, int N) {
    const int tid = threadIdx.x;
    const int wv = tid >> 6;
    const int lane = tid & 63;
    const int n = blockIdx.x * 4 + wv;
    if (n >= N) return;
    const int c0 = lane * 4;
    const ushort4 qu = *reinterpret_cast<const ushort4*>(qkvs + (size_t)n * 1024 + c0);
    const float q0 = us2f(qu.x), q1 = us2f(qu.y), q2 = us2f(qu.z), q3 = us2f(qu.w);
    float a0 = 0.f, a1 = 0.f, a2 = 0.f, a3 = 0.f, wsum = 0.f;
    const int e0 = indptr[n], e1 = indptr[n + 1];
    const char* __restrict__ kvb = (const char*)qkvs + 1024 + lane * 16;
    const char* __restrict__ epb = (const char*)ecp + c0 * 4;

    auto edge_body = [&](const uint4& kv, const float4& ep) {
        const float k0 = us2f((unsigned short)(kv.x & 0xffff)), k1 = us2f((unsigned short)(kv.x >> 16));
        const float k2 = us2f((unsigned short)(kv.y & 0xffff)), k3 = us2f((unsigned short)(kv.y >> 16));
        const float v0 = us2f((unsigned short)(kv.z & 0xffff)), v1 = us2f((unsigned short)(kv.z >> 16));
        const float v2 = us2f((unsigned short)(kv.w & 0xffff)), v3 = us2f((unsigned short)(kv.w >> 16));
        float t = q0 * (k0 + ep.x) + q1 * (k1 + ep.y) + q2 * (k2 + ep.z) + q3 * (k3 + ep.w);
        t = row_ror_add<0x121>(t);
        t = row_ror_add<0x122>(t);
        t = row_ror_add<0x124>(t);
        t = row_ror_add<0x128>(t);
        const float w = __expf(t * 0.125f);
        a0 += w * (v0 + ep.x);
        a1 += w * (v1 + ep.y);
        a2 += w * (v2 + ep.z);
        a3 += w * (v3 + ep.w);
        wsum += w;
    };

    if (e0 < e1) {
        int2 m0 = sorted2[e0];
        int2 m1 = sorted2[e0 + 1];
        uint4 kv0 = *reinterpret_cast<const uint4*>(kvb + (unsigned)m0.x);
        uint4 kv1 = *reinterpret_cast<const uint4*>(kvb + (unsigned)m1.x);
        int ee = e0;
        for (; ee + 1 < e1; ee += 2) {
            const int2 mN0 = sorted2[ee + 2];
            const int2 mN1 = sorted2[ee + 3];
            const uint4 kvN0 = *reinterpret_cast<const uint4*>(kvb + (unsigned)mN0.x);
            const uint4 kvN1 = *reinterpret_cast<const uint4*>(kvb + (unsigned)mN1.x);
            const float4 ep0 = *reinterpret_cast<const float4*>(epb + (unsigned)m0.y);
            const float4 ep1 = *reinterpret_cast<const float4*>(epb + (unsigned)m1.y);
            edge_body(kv0, ep0);
            edge_body(kv1, ep1);
            m0 = mN0; m1 = mN1;
            kv0 = kvN0; kv1 = kvN1;
        }
        if (ee < e1) {
            const float4 ep0 = *reinterpret_cast<const float4*>(epb + (unsigned)m0.y);
            edge_body(kv0, ep0);
        }
    }
    const float inv = (wsum > 0.f) ? 1.f / wsum : 0.f;
    const float o0 = a0 * inv, o1 = a1 * inv, o2 = a2 * inv, o3 = a3 * inv;
    const ushort4 ru = *reinterpret_cast<const ushort4*>(qkvs + (size_t)n * 1024 + 256 + c0);
    const float r0 = us2f(ru.x), r1 = us2f(ru.y), r2 = us2f(ru.z), r3 = us2f(ru.w);
    const float4 w1 = *reinterpret_cast<const float4*>(Wbeta_l + c0);
    const float4 w2 = *reinterpret_cast<const float4*>(Wbeta_l + 256 + c0);
    const float4 w3 = *reinterpret_cast<const float4*>(Wbeta_l + 512 + c0);
    float tb = o0 * w1.x + o1 * w1.y + o2 * w1.z + o3 * w1.w
             + r0 * w2.x + r1 * w2.y + r2 * w2.z + r3 * w2.w
             + (o0 - r0) * w3.x + (o1 - r1) * w3.y + (o2 - r2) * w3.z + (o3 - r3) * w3.w;
#pragma unroll
    for (int off = 32; off > 0; off >>= 1) tb += __shfl_xor(tb, off);
    const float beta = 1.f / (1.f + __expf(-tb));
    float g0 = fmaxf(beta * r0 + (1.f - beta) * o0, 0.f);
    float g1 = fmaxf(beta * r1 + (1.f - beta) * o1, 0.f);
    float g2 = fmaxf(beta * r2 + (1.f - beta) * o2, 0.f);
    float g3 = fmaxf(beta * r3 + (1.f - beta) * o3, 0.f);
    float s1 = g0 + g1 + g2 + g3;
    float s2 = g0 * g0 + g1 * g1 + g2 * g2 + g3 * g3;
#pragma unroll
    for (int off = 32; off > 0; off >>= 1) { s1 += __shfl_xor(s1, off); s2 += __shfl_xor(s2, off); }
    const float mu = s1 * (1.f / 256.f);
    const float var = s2 * (1.f / 256.f) - mu * mu;
    const float rish = rsqrtf(fmaxf(var, 0.f) + 1e-5f);
    const float4 gg = *reinterpret_cast<const float4*>(lng + c0);
    const float4 bb = *reinterpret_cast<const float4*>(lnb + c0);
    ushort4 hb = *reinterpret_cast<ushort4*>(hbf + (size_t)n * HID + c0);
    float h0 = us2f(hb.x) + (g0 - mu) * rish * gg.x + bb.x;
    float h1 = us2f(hb.y) + (g1 - mu) * rish * gg.y + bb.y;
    float h2 = us2f(hb.z) + (g2 - mu) * rish * gg.z + bb.z;
    float h3 = us2f(hb.w) + (g3 - mu) * rish * gg.w + bb.w;
    hb.x = f2us(h0); hb.y = f2us(h1); hb.z = f2us(h2); hb.w = f2us(h3);
    *reinterpret_cast<ushort4*>(hbf + (size_t)n * HID + c0) = hb;
}

// ---------------- hierarchical pooling (reads bf16 h) ----------------
__global__ __launch_bounds__(256) void pool_kernel(const bf16* __restrict__ hbf,
                                                   const int* __restrict__ batch,
                                                   float* __restrict__ pooled, int N) {
    __shared__ int sb[64];
    const int c = threadIdx.x;
    const int n0 = blockIdx.x * 64;
    const int cnt = min(64, N - n0);
    if (c < 64 && c < cnt) sb[c] = batch[n0 + c];
    __syncthreads();
    float acc = 0.f;
    int gcur = sb[0];
    for (int i = 0; i < cnt; ++i) {
        const int g = sb[i];
        if (g != gcur) {
            atomicAdd(&pooled[(size_t)gcur * HID + c], acc);
            acc = 0.f;
            gcur = g;
        }
        acc += b2f(hbf[(size_t)(n0 + i) * HID + c]);
    }
    atomicAdd(&pooled[(size_t)gcur * HID + c], acc);
}

__global__ void pragma_kernel(const float* __restrict__ scalars,
                              const float* __restrict__ pw1, const float* __restrict__ pb1,
                              const float* __restrict__ pw2, const float* __restrict__ pb2,
                              float* __restrict__ pooled) {
    int g = blockIdx.x, c = threadIdx.x;
    __shared__ float s5[5];
    __shared__ float t1[256];
    if (c < 5) s5[c] = scalars[g * 5 + c];
    __syncthreads();
    float a = pb1[c];
    for (int k = 0; k < 5; ++k) a += s5[k] * pw1[k * 256 + c];
    t1[c] = fmaxf(a, 0.f);
    __syncthreads();
    float p = pb2[c];
    for (int j = 0; j < 256; ++j) p += t1[j] * pw2[j * 256 + c];
    pooled[g * 256 + c] += p;
}

__global__ void readout_kernel(const float* __restrict__ pooled,
                               const float* __restrict__ rw1, const float* __restrict__ rb1,
                               const float* __restrict__ rw2, const float* __restrict__ rb2,
                               const float* __restrict__ rw3, const float* __restrict__ rb3,
                               float* __restrict__ out) {
    int g = blockIdx.x, c = threadIdx.x;
    __shared__ float pl[256], z1[256], z2[128];
    pl[c] = pooled[g * 256 + c];
    __syncthreads();
    float z = rb1[c];
    for (int k = 0; k < 256; ++k) z += pl[k] * rw1[k * 256 + c];
    z1[c] = fmaxf(z, 0.f);
    __syncthreads();
    if (c < 128) {
        float v = rb2[c];
        for (int j = 0; j < 256; ++j) v += z1[j] * rw2[j * 128 + c];
        z2[c] = fmaxf(v, 0.f);
    }
    __syncthreads();
    if (c < 4) {
        float o = rb3[c];
        for (int j = 0; j < 128; ++j) o += z2[j] * rw3[j * 4 + c];
        out[g * 4 + c] = o;
    }
}

extern "C" void kernel_launch(void* const* d_in, const int* in_sizes, int n_in,
                              void* d_out, int out_size, void* d_ws, size_t ws_size,
                              hipStream_t stream) {
    const int* x          = (const int*)d_in[0];
    const int* edge_attr  = (const int*)d_in[1];
    const int* edge_index = (const int*)d_in[2];
    const int* batch      = (const int*)d_in[3];
    const float* scalars  = (const float*)d_in[4];
    const float* ne0 = (const float*)d_in[6];
    const float* ne1 = (const float*)d_in[7];
    const float* ne2 = (const float*)d_in[8];
    const float* ee0 = (const float*)d_in[9];
    const float* ee1 = (const float*)d_in[10];
    const float* Wq = (const float*)d_in[11];
    const float* bq = (const float*)d_in[12];
    const float* Wk = (const float*)d_in[13];
    const float* bk = (const float*)d_in[14];
    const float* Wv = (const float*)d_in[15];
    const float* bv = (const float*)d_in[16];
    const float* We = (const float*)d_in[17];
    const float* be = (const float*)d_in[18];
    const float* Wskip = (const float*)d_in[19];
    const float* bskip = (const float*)d_in[20];
    const float* Wbeta = (const float*)d_in[21];
    const float* ln_g = (const float*)d_in[22];
    const float* ln_b = (const float*)d_in[23];
    const float* pw1 = (const float*)d_in[24];
    const float* pb1 = (const float*)d_in[25];
    const float* pw2 = (const float*)d_in[26];
    const float* pb2 = (const float*)d_in[27];
    const float* rw1 = (const float*)d_in[28];
    const float* rb1 = (const float*)d_in[29];
    const float* rw2 = (const float*)d_in[30];
    const float* rb2 = (const float*)d_in[31];
    const float* rw3 = (const float*)d_in[32];
    const float* rb3 = (const float*)d_in[33];

    const int N = in_sizes[0] / 3;
    const int E = in_sizes[1] / 2;
    const int G = in_sizes[4] / 5;

    char* base = (char*)d_ws;
    size_t off = 0;
    auto carve = [&](size_t bytes) -> char* {
        char* p = base + off;
        off += (bytes + 255) & ~(size_t)255;
        return p;
    };
    bf16*  hbf    = (bf16*)carve((size_t)N * HID * 2);
    bf16*  qkvs   = (bf16*)carve((size_t)N * 1024 * 2);
    float* ec     = (float*)carve((size_t)32 * HID * 4);
    float* ecp4   = (float*)carve((size_t)NL * 32 * HID * 4);
    int*   ecid   = (int*)carve((size_t)E * 4);
    float* pooled = (float*)carve((size_t)G * HID * 4);
    bf16*  wcatT  = (bf16*)carve((size_t)NL * 1024 * 256 * 2);
    float* bcat   = (float*)carve((size_t)NL * 1024 * 4);
    int* counts   = (int*)carve((size_t)N * 4);
    int* fill     = (int*)carve((size_t)N * 4);
    int* incl     = (int*)carve((size_t)N * 4);
    int* bsum     = (int*)carve(4096);
    int* boff     = (int*)carve(4096);
    int* indptr   = (int*)carve((size_t)(N + 1) * 4);
    int2* sorted2 = (int2*)carve((size_t)(E + 4) * 8);   // +4 pad for unclamped pair prefetch
    // total ~140 MB

    const int* srcv = edge_index;
    const int* dstv = edge_index + E;

    zero_ws_kernel<<<(N + 255) / 256, 256, 0, stream>>>(counts, fill, N, pooled, G * HID);
    node_embed_kernel<<<(N + 3) / 4, 256, 0, stream>>>(x, ne0, ne1, ne2, hbf, N);
    ecombo_embed_kernel<<<32, 256, 0, stream>>>(ee0, ee1, ec);
    edge_prep_kernel<<<(E + 255) / 256, 256, 0, stream>>>(edge_attr, dstv, E, ecid, counts);
    {
        dim3 gp(16, 4, 4);
        pack_wcat_kernel<<<gp, 256, 0, stream>>>(Wq, Wk, Wv, Wskip, wcatT);
    }
    pack_bias_kernel<<<16, 256, 0, stream>>>(bq, bk, bv, bskip, bcat);
    combo_proj_kernel<<<NL * 32, 256, 0, stream>>>(ec, We, be, ecp4);

    int nsb = (N + 255) / 256;
    scan_local_kernel<<<nsb, 256, 0, stream>>>(counts, N, incl, bsum);
    scan_block_kernel<<<1, 256, 0, stream>>>(bsum, nsb, boff);
    scan_add_kernel<<<nsb, 256, 0, stream>>>(incl, boff, N, indptr);
    fill_sorted_kernel<<<(E + 255) / 256, 256, 0, stream>>>(dstv, srcv, ecid, indptr, E, fill, sorted2);

    for (int l = 0; l < NL; ++l) {
        gemm_reg_kernel<<<6272, 256, 0, stream>>>(hbf, wcatT + (size_t)l * 262144,
                                                  bcat + (size_t)l * 1024, qkvs, N);
        attn_node_kernel<<<(N + 3) / 4, 256, 0, stream>>>(qkvs, ecp4 + (size_t)l * 32 * HID,
                                                          indptr, sorted2,
                                                          Wbeta + (size_t)l * 768,
                                                          ln_g + (size_t)l * 256, ln_b + (size_t)l * 256,
                                                          hbf, N);
    }

    pool_kernel<<<(N + 63) / 64, 256, 0, stream>>>(hbf, batch, pooled, N);
    pragma_kernel<<<G, 256, 0, stream>>>(scalars, pw1, pb1, pw2, pb2, pooled);
    readout_kernel<<<G, 256, 0, stream>>>(pooled, rw1, rb1, rw2, rb2, rw3, rb3, (float*)d_out);
}

// Round 10
// 668.851 us; speedup vs baseline: 1.4948x; 1.4948x over previous
//
#include <hip/hip_runtime.h>
#include <hip/hip_bf16.h>

typedef short short8 __attribute__((ext_vector_type(8)));
typedef float floatx4 __attribute__((ext_vector_type(4)));
typedef float floatx2 __attribute__((ext_vector_type(2)));
typedef __hip_bfloat16 bf16;

#define HID 256
#define NL  4
#define QROW 1536   // qkvs row bytes: 512 q(bf16) | 512 skip(bf16) | 512 kv(fp8)
#define AS1 __attribute__((address_space(1)))
#define AS3 __attribute__((address_space(3)))

__device__ __forceinline__ float b2f(bf16 v) { return __bfloat162float(v); }
__device__ __forceinline__ bf16 f2b(float v) { return __float2bfloat16(v); }
__device__ __forceinline__ float us2f(unsigned short u) {
    unsigned int x = ((unsigned int)u) << 16;
    return __uint_as_float(x);
}
__device__ __forceinline__ unsigned short f2us(float v) {
    bf16 t = __float2bfloat16(v);
    return *reinterpret_cast<unsigned short*>(&t);
}

// DPP row-rotate add: sum within each 16-lane row, 4 steps, pure VALU pipe.
template <int CTRL>
__device__ __forceinline__ float row_ror_add(float x) {
    return x + __int_as_float(__builtin_amdgcn_update_dpp(
        0, __float_as_int(x), CTRL, 0xF, 0xF, true));
}

// ---------------- fused zero-init: counts, fill (N each) + pooled (G*HID) ----------------
__global__ void zero_ws_kernel(int* __restrict__ a, int* __restrict__ b, int n,
                               float* __restrict__ p, int np) {
    int i = blockIdx.x * 256 + threadIdx.x;
    if (i < n) { a[i] = 0; b[i] = 0; }
    if (i < np) p[i] = 0.f;
}

// ---------------- embeddings; float4 loads, 4 nodes/block ----------------
__global__ __launch_bounds__(256) void node_embed_kernel(const int* __restrict__ x,
                                  const float* __restrict__ e0, const float* __restrict__ e1,
                                  const float* __restrict__ e2,
                                  bf16* __restrict__ hbf, int N) {
    const int tid = threadIdx.x;
    const int n = blockIdx.x * 4 + (tid >> 6);
    if (n >= N) return;
    const int c4 = (tid & 63) * 4;
    const int i0 = x[n * 3], i1 = x[n * 3 + 1], i2 = x[n * 3 + 2];
    const float4 a = *reinterpret_cast<const float4*>(e0 + i0 * HID + c4);
    const float4 b = *reinterpret_cast<const float4*>(e1 + i1 * HID + c4);
    const float4 c = *reinterpret_cast<const float4*>(e2 + i2 * HID + c4);
    ushort4 o;
    o.x = f2us(a.x + b.x + c.x);
    o.y = f2us(a.y + b.y + c.y);
    o.z = f2us(a.z + b.z + c.z);
    o.w = f2us(a.w + b.w + c.w);
    *reinterpret_cast<ushort4*>(hbf + (size_t)n * HID + c4) = o;
}

__global__ void ecombo_embed_kernel(const float* __restrict__ e0, const float* __restrict__ e1,
                                    float* __restrict__ ec) {
    int i = blockIdx.x, c = threadIdx.x;
    ec[i * HID + c] = e0[(i >> 2) * HID + c] + e1[(i & 3) * HID + c];
}

// merged: per-edge combo id + dst histogram (one pass over edges)
__global__ void edge_prep_kernel(const int* __restrict__ ea, const int* __restrict__ dst,
                                 int E, int* __restrict__ ecid, int* __restrict__ counts) {
    int e = blockIdx.x * 256 + threadIdx.x;
    if (e < E) {
        ecid[e] = ea[e * 2] * 4 + ea[e * 2 + 1];
        atomicAdd(&counts[dst[e]], 1);
    }
}

// ALL layers at once: blockIdx.x = l*32 + i -> ecp4[l][i][c]
__global__ void combo_proj_kernel(const float* __restrict__ ec, const float* __restrict__ We,
                                  const float* __restrict__ be, float* __restrict__ ecp4) {
    __shared__ float row[HID];
    int l = blockIdx.x >> 5, i = blockIdx.x & 31, c = threadIdx.x;
    row[c] = ec[i * HID + c];
    __syncthreads();
    const float* We_l = We + (size_t)l * 65536;
    float a = be[l * 256 + c];
    for (int k = 0; k < HID; ++k) a += row[k] * We_l[k * HID + c];
    ecp4[(size_t)l * 32 * HID + i * HID + c] = a;
}

// ---------------- CSR scan ----------------
__global__ void scan_local_kernel(const int* __restrict__ counts, int N,
                                  int* __restrict__ incl, int* __restrict__ bsum) {
    __shared__ int sd[256];
    int i = threadIdx.x;
    int idx = blockIdx.x * 256 + i;
    sd[i] = (idx < N) ? counts[idx] : 0;
    __syncthreads();
    for (int off = 1; off < 256; off <<= 1) {
        int t = (i >= off) ? sd[i - off] : 0;
        __syncthreads();
        sd[i] += t;
        __syncthreads();
    }
    if (idx < N) incl[idx] = sd[i];
    if (i == 255) bsum[blockIdx.x] = sd[255];
}

__global__ void scan_block_kernel(const int* __restrict__ bsum, int nb, int* __restrict__ boff) {
    __shared__ int sd[256];
    int i = threadIdx.x;
    sd[i] = (i < nb) ? bsum[i] : 0;
    __syncthreads();
    for (int off = 1; off < 256; off <<= 1) {
        int t = (i >= off) ? sd[i - off] : 0;
        __syncthreads();
        sd[i] += t;
        __syncthreads();
    }
    if (i < nb) boff[i] = (i == 0) ? 0 : sd[i - 1];
}

__global__ void scan_add_kernel(const int* __restrict__ incl, const int* __restrict__ boff,
                                int N, int* __restrict__ indptr) {
    int idx = blockIdx.x * 256 + threadIdx.x;
    if (idx < N) indptr[idx + 1] = incl[idx] + boff[blockIdx.x];
    if (idx == 0) indptr[0] = 0;
}

// sorted2: PRE-SCALED BYTE OFFSETS (x = src*1536 qkvs row, y = ecid*1024 ecp row). +4 pad.
__global__ void fill_sorted_kernel(const int* __restrict__ dst, const int* __restrict__ srcv,
                                   const int* __restrict__ ecid, const int* __restrict__ indptr,
                                   int E, int* __restrict__ fill, int2* __restrict__ sorted2) {
    int e = blockIdx.x * 256 + threadIdx.x;
    if (e < E) {
        int d = dst[e];
        int pos = indptr[d] + atomicAdd(&fill[d], 1);
        sorted2[pos] = make_int2(srcv[e] * QROW, ecid[e] << 10);
    }
    if (e < 4) sorted2[E + e] = make_int2(0, 0);
}

// ---------------- weight packing: LDS-transposed, coalesced both sides ----------------
__global__ __launch_bounds__(256) void pack_wcat_kernel(
    const float* __restrict__ Wq, const float* __restrict__ Wk,
    const float* __restrict__ Wv, const float* __restrict__ Ws,
    bf16* __restrict__ wcatT) {
    __shared__ bf16 tile[64][65];
    const int jt = blockIdx.x;     // 0..15  (j tile of 64)
    const int kt = blockIdx.y;     // 0..3   (k tile of 64)
    const int l  = blockIdx.z;     // 0..3
    const int tid = threadIdx.x;
    const int jl = tid & 63;
    const int j = jt * 64 + jl;
    const float* W;
    int jj;
    if (j < 256)      { W = Wq; jj = j; }
    else if (j < 512) { W = Ws; jj = j - 256; }
    else {
        int g = (j - 512) >> 3, r = (j - 512) & 7;
        if (r < 4) { W = Wk; jj = 4 * g + r; }
        else       { W = Wv; jj = 4 * g + r - 4; }
    }
    const float* Wbase = W + (size_t)l * 65536 + jj + (size_t)(kt * 64) * 256;
    const int kr = tid >> 6;       // 0..3
#pragma unroll
    for (int i = 0; i < 16; ++i) {
        const int kl = kr + i * 4;
        tile[kl][jl] = f2b(Wbase[(size_t)kl * 256]);
    }
    __syncthreads();
    const int kl2 = tid & 63;
    const int jr = tid >> 6;
    bf16* out = wcatT + (size_t)l * 262144 + (size_t)(jt * 64) * 256 + kt * 64 + kl2;
#pragma unroll
    for (int i = 0; i < 16; ++i) {
        const int jl2 = jr + i * 4;
        out[(size_t)jl2 * 256] = tile[kl2][jl2];
    }
}

__global__ void pack_bias_kernel(const float* __restrict__ bq, const float* __restrict__ bk,
                                 const float* __restrict__ bv, const float* __restrict__ bs,
                                 float* __restrict__ bcat) {
    int idx = blockIdx.x * 256 + threadIdx.x;      // < 4096
    if (idx < 4096) {
        int l = idx >> 10, j = idx & 1023;
        const float* B;
        int jj;
        if (j < 256)      { B = bq; jj = j; }
        else if (j < 512) { B = bs; jj = j - 256; }
        else {
            int g = (j - 512) >> 3, r = (j - 512) & 7;
            if (r < 4) { B = bk; jj = 4 * g + r; }
            else       { B = bv; jj = 4 * g + r - 4; }
        }
        bcat[idx] = B[l * 256 + jj];
    }
}

// ---------------- MFMA GEMM (R30): proven R24 tile structure + one-shot fp8-kv epilogue ----
// R29 post-mortem: reg-B defeated by regalloc (VGPR=52 -> compiler rematerialized B loads in
// the loop, MfmaUtil 7%). gemm_bt (69.7us) is the measured floor across 4 structures -> keep
// it. New: kv half (col-tiles n0>=512, block-uniform branch) converts to OCP fp8 in the
// ONE-SHOT epilogue (~48 VALU/thread once per block -- unlike R27's per-m-step conversion).
// C row = 1536B; write traffic 100->78MB; attn gather bytes halve.
__global__ __launch_bounds__(512) void gemm_bt_kernel(
    const bf16* __restrict__ A, const bf16* __restrict__ BT,
    const float* __restrict__ bias, char* __restrict__ Cb, int M) {
    constexpr int BM = 128, BN = 256, BK = 64, CSTR = 136;
    __shared__ __align__(16) bf16 smem[BM * 64 + BN * 64];   // 48 KB
    bf16* sA = smem;
    bf16* sB = smem + BM * 64;
    const int m0 = blockIdx.y * BM;
    const int n0 = blockIdx.x * BN;
    const int tid = threadIdx.x;
    const int lane = tid & 63;
    const int wave = tid >> 6;
    const int wm = (wave >> 2) * 64;
    const int wn = (wave & 3) * 64;
    const int fr = lane & 15;
    const int quad = lane >> 4;
    const int sub = lane >> 3;
    const int slot = lane & 7;
    const int jsw = slot ^ sub;
    const bool isfp8 = (n0 >= 512);
    floatx4 acc[4][4] = {};
    for (int kc = 0; kc < 256; kc += BK) {
#pragma unroll
        for (int p = 0; p < 2; ++p) {
            const int brow = (wave * 2 + p) * 8;
            const int gm = min(m0 + brow + sub, M - 1);
            __builtin_amdgcn_global_load_lds(
                (const AS1 void*)(A + (size_t)gm * 256 + kc + jsw * 8),
                (AS3 void*)(sA + brow * 64), 16, 0, 0);
        }
#pragma unroll
        for (int p = 0; p < 4; ++p) {
            const int brow = (wave * 4 + p) * 8;
            __builtin_amdgcn_global_load_lds(
                (const AS1 void*)(BT + (size_t)(n0 + brow + sub) * 256 + kc + jsw * 8),
                (AS3 void*)(sB + brow * 64), 16, 0, 0);
        }
        __syncthreads();
#pragma unroll
        for (int ks = 0; ks < BK; ks += 32) {
            const int ch = (ks >> 3) + quad;
            const int phys = (ch ^ (fr & 7)) << 3;
            short8 af[4], bfm[4];
#pragma unroll
            for (int i = 0; i < 4; ++i) {
                af[i]  = *reinterpret_cast<const short8*>(&sA[(wm + i * 16 + fr) * 64 + phys]);
                bfm[i] = *reinterpret_cast<const short8*>(&sB[(wn + i * 16 + fr) * 64 + phys]);
            }
#pragma unroll
            for (int mi = 0; mi < 4; ++mi)
#pragma unroll
                for (int ni = 0; ni < 4; ++ni)
                    acc[mi][ni] = __builtin_amdgcn_mfma_f32_16x16x32_bf16(af[mi], bfm[ni], acc[mi][ni], 0, 0, 0);
        }
        __syncthreads();
    }
    float bias4[4];
#pragma unroll
    for (int ni = 0; ni < 4; ++ni) bias4[ni] = bias[n0 + wn + ni * 16 + fr];
    bf16* sC = smem;
    const int myhalf = wn >> 7;
#pragma unroll
    for (int half = 0; half < 2; ++half) {
        if (myhalf == half) {
            const int wnl = wn & 127;
#pragma unroll
            for (int mi = 0; mi < 4; ++mi)
#pragma unroll
                for (int ni = 0; ni < 4; ++ni)
#pragma unroll
                    for (int r = 0; r < 4; ++r)
                        sC[(wm + mi * 16 + quad * 4 + r) * CSTR + wnl + ni * 16 + fr] =
                            f2b(acc[mi][ni][r] + bias4[ni]);
        }
        __syncthreads();
#pragma unroll
        for (int p = 0; p < 4; ++p) {
            int ci = tid + p * 512;
            int row = ci >> 4;
            int c8 = (ci & 15) << 3;
            if (m0 + row < M) {
                const uint4 vv = *reinterpret_cast<const uint4*>(&sC[row * CSTR + c8]);
                char* crow = Cb + (size_t)(m0 + row) * QROW;
                const int col = n0 + half * 128 + c8;
                if (!isfp8) {
                    *reinterpret_cast<uint4*>(crow + col * 2) = vv;
                } else {
                    const float f0 = us2f((unsigned short)(vv.x & 0xffff)), f1 = us2f((unsigned short)(vv.x >> 16));
                    const float f2 = us2f((unsigned short)(vv.y & 0xffff)), f3 = us2f((unsigned short)(vv.y >> 16));
                    const float f4 = us2f((unsigned short)(vv.z & 0xffff)), f5 = us2f((unsigned short)(vv.z >> 16));
                    const float f6 = us2f((unsigned short)(vv.w & 0xffff)), f7 = us2f((unsigned short)(vv.w >> 16));
                    int lo = 0, hi = 0;
                    lo = __builtin_amdgcn_cvt_pk_fp8_f32(f0, f1, lo, false);
                    lo = __builtin_amdgcn_cvt_pk_fp8_f32(f2, f3, lo, true);
                    hi = __builtin_amdgcn_cvt_pk_fp8_f32(f4, f5, hi, false);
                    hi = __builtin_amdgcn_cvt_pk_fp8_f32(f6, f7, hi, true);
                    uint2 o;
                    o.x = (unsigned)lo;
                    o.y = (unsigned)hi;
                    *reinterpret_cast<uint2*>(crow + 1024 + (col - 512)) = o;
                }
            }
        }
        __syncthreads();
    }
}

// ---------------- fused attention: wave-per-node, fp8 kv gather (R27-proven) ----------------
__global__ __launch_bounds__(256) void attn_node_kernel(
    const char* __restrict__ qkvs,     // [N,1536B] q bf16 | skip bf16 | kv fp8 interleaved
    const float* __restrict__ ecp,     // [32,256] this layer
    const int* __restrict__ indptr, const int2* __restrict__ sorted2,
    const float* __restrict__ Wbeta_l, const float* __restrict__ lng, const float* __restrict__ lnb,
    bf16* __restrict__ hbf, int N) {
    const int tid = threadIdx.x;
    const int wv = tid >> 6;
    const int lane = tid & 63;
    const int n = blockIdx.x * 4 + wv;
    if (n >= N) return;
    const int c0 = lane * 4;
    const ushort4 qu = *reinterpret_cast<const ushort4*>(qkvs + (size_t)n * QROW + lane * 8);
    const float q0 = us2f(qu.x), q1 = us2f(qu.y), q2 = us2f(qu.z), q3 = us2f(qu.w);
    float a0 = 0.f, a1 = 0.f, a2 = 0.f, a3 = 0.f, wsum = 0.f;
    const int e0 = indptr[n], e1 = indptr[n + 1];
    const char* __restrict__ kvb = qkvs + 1024 + lane * 8;   // + src*1536 per edge
    const char* __restrict__ epb = (const char*)ecp + c0 * 4;

    auto edge_body = [&](const uint2& kv, const float4& ep) {
        const floatx2 ka = __builtin_amdgcn_cvt_pk_f32_fp8(kv.x, false);
        const floatx2 kb = __builtin_amdgcn_cvt_pk_f32_fp8(kv.x, true);
        const floatx2 va = __builtin_amdgcn_cvt_pk_f32_fp8(kv.y, false);
        const floatx2 vb = __builtin_amdgcn_cvt_pk_f32_fp8(kv.y, true);
        float t = q0 * (ka.x + ep.x) + q1 * (ka.y + ep.y) + q2 * (kb.x + ep.z) + q3 * (kb.y + ep.w);
        t = row_ror_add<0x121>(t);
        t = row_ror_add<0x122>(t);
        t = row_ror_add<0x124>(t);
        t = row_ror_add<0x128>(t);
        const float w = __expf(t * 0.125f);
        a0 += w * (va.x + ep.x);
        a1 += w * (va.y + ep.y);
        a2 += w * (vb.x + ep.z);
        a3 += w * (vb.y + ep.w);
        wsum += w;
    };

    if (e0 < e1) {
        int2 m0 = sorted2[e0];
        int2 m1 = sorted2[e0 + 1];                 // pad makes this safe
        uint2 kv0 = *reinterpret_cast<const uint2*>(kvb + (unsigned)m0.x);
        uint2 kv1 = *reinterpret_cast<const uint2*>(kvb + (unsigned)m1.x);
        int ee = e0;
        for (; ee + 1 < e1; ee += 2) {
            const int2 mN0 = sorted2[ee + 2];
            const int2 mN1 = sorted2[ee + 3];
            const uint2 kvN0 = *reinterpret_cast<const uint2*>(kvb + (unsigned)mN0.x);
            const uint2 kvN1 = *reinterpret_cast<const uint2*>(kvb + (unsigned)mN1.x);
            const float4 ep0 = *reinterpret_cast<const float4*>(epb + (unsigned)m0.y);
            const float4 ep1 = *reinterpret_cast<const float4*>(epb + (unsigned)m1.y);
            edge_body(kv0, ep0);
            edge_body(kv1, ep1);
            m0 = mN0; m1 = mN1;
            kv0 = kvN0; kv1 = kvN1;
        }
        if (ee < e1) {                             // odd degree: slot0 holds edge ee
            const float4 ep0 = *reinterpret_cast<const float4*>(epb + (unsigned)m0.y);
            edge_body(kv0, ep0);
        }
    }
    const float inv = (wsum > 0.f) ? 1.f / wsum : 0.f;
    const float o0 = a0 * inv, o1 = a1 * inv, o2 = a2 * inv, o3 = a3 * inv;
    const ushort4 ru = *reinterpret_cast<const ushort4*>(qkvs + (size_t)n * QROW + 512 + lane * 8);
    const float r0 = us2f(ru.x), r1 = us2f(ru.y), r2 = us2f(ru.z), r3 = us2f(ru.w);
    const float4 w1 = *reinterpret_cast<const float4*>(Wbeta_l + c0);
    const float4 w2 = *reinterpret_cast<const float4*>(Wbeta_l + 256 + c0);
    const float4 w3 = *reinterpret_cast<const float4*>(Wbeta_l + 512 + c0);
    float tb = o0 * w1.x + o1 * w1.y + o2 * w1.z + o3 * w1.w
             + r0 * w2.x + r1 * w2.y + r2 * w2.z + r3 * w2.w
             + (o0 - r0) * w3.x + (o1 - r1) * w3.y + (o2 - r2) * w3.z + (o3 - r3) * w3.w;
#pragma unroll
    for (int off = 32; off > 0; off >>= 1) tb += __shfl_xor(tb, off);
    const float beta = 1.f / (1.f + __expf(-tb));
    float g0 = fmaxf(beta * r0 + (1.f - beta) * o0, 0.f);
    float g1 = fmaxf(beta * r1 + (1.f - beta) * o1, 0.f);
    float g2 = fmaxf(beta * r2 + (1.f - beta) * o2, 0.f);
    float g3 = fmaxf(beta * r3 + (1.f - beta) * o3, 0.f);
    float s1 = g0 + g1 + g2 + g3;
    float s2 = g0 * g0 + g1 * g1 + g2 * g2 + g3 * g3;
#pragma unroll
    for (int off = 32; off > 0; off >>= 1) { s1 += __shfl_xor(s1, off); s2 += __shfl_xor(s2, off); }
    const float mu = s1 * (1.f / 256.f);
    const float var = s2 * (1.f / 256.f) - mu * mu;
    const float rish = rsqrtf(fmaxf(var, 0.f) + 1e-5f);
    const float4 gg = *reinterpret_cast<const float4*>(lng + c0);
    const float4 bb = *reinterpret_cast<const float4*>(lnb + c0);
    ushort4 hb = *reinterpret_cast<ushort4*>(hbf + (size_t)n * HID + c0);
    float h0 = us2f(hb.x) + (g0 - mu) * rish * gg.x + bb.x;
    float h1 = us2f(hb.y) + (g1 - mu) * rish * gg.y + bb.y;
    float h2 = us2f(hb.z) + (g2 - mu) * rish * gg.z + bb.z;
    float h3 = us2f(hb.w) + (g3 - mu) * rish * gg.w + bb.w;
    hb.x = f2us(h0); hb.y = f2us(h1); hb.z = f2us(h2); hb.w = f2us(h3);
    *reinterpret_cast<ushort4*>(hbf + (size_t)n * HID + c0) = hb;
}

// ---------------- hierarchical pooling (reads bf16 h) ----------------
__global__ __launch_bounds__(256) void pool_kernel(const bf16* __restrict__ hbf,
                                                   const int* __restrict__ batch,
                                                   float* __restrict__ pooled, int N) {
    __shared__ int sb[64];
    const int c = threadIdx.x;
    const int n0 = blockIdx.x * 64;
    const int cnt = min(64, N - n0);
    if (c < 64 && c < cnt) sb[c] = batch[n0 + c];
    __syncthreads();
    float acc = 0.f;
    int gcur = sb[0];
    for (int i = 0; i < cnt; ++i) {
        const int g = sb[i];
        if (g != gcur) {
            atomicAdd(&pooled[(size_t)gcur * HID + c], acc);
            acc = 0.f;
            gcur = g;
        }
        acc += b2f(hbf[(size_t)(n0 + i) * HID + c]);
    }
    atomicAdd(&pooled[(size_t)gcur * HID + c], acc);
}

__global__ void pragma_kernel(const float* __restrict__ scalars,
                              const float* __restrict__ pw1, const float* __restrict__ pb1,
                              const float* __restrict__ pw2, const float* __restrict__ pb2,
                              float* __restrict__ pooled) {
    int g = blockIdx.x, c = threadIdx.x;
    __shared__ float s5[5];
    __shared__ float t1[256];
    if (c < 5) s5[c] = scalars[g * 5 + c];
    __syncthreads();
    float a = pb1[c];
    for (int k = 0; k < 5; ++k) a += s5[k] * pw1[k * 256 + c];
    t1[c] = fmaxf(a, 0.f);
    __syncthreads();
    float p = pb2[c];
    for (int j = 0; j < 256; ++j) p += t1[j] * pw2[j * 256 + c];
    pooled[g * 256 + c] += p;
}

__global__ void readout_kernel(const float* __restrict__ pooled,
                               const float* __restrict__ rw1, const float* __restrict__ rb1,
                               const float* __restrict__ rw2, const float* __restrict__ rb2,
                               const float* __restrict__ rw3, const float* __restrict__ rb3,
                               float* __restrict__ out) {
    int g = blockIdx.x, c = threadIdx.x;
    __shared__ float pl[256], z1[256], z2[128];
    pl[c] = pooled[g * 256 + c];
    __syncthreads();
    float z = rb1[c];
    for (int k = 0; k < 256; ++k) z += pl[k] * rw1[k * 256 + c];
    z1[c] = fmaxf(z, 0.f);
    __syncthreads();
    if (c < 128) {
        float v = rb2[c];
        for (int j = 0; j < 256; ++j) v += z1[j] * rw2[j * 128 + c];
        z2[c] = fmaxf(v, 0.f);
    }
    __syncthreads();
    if (c < 4) {
        float o = rb3[c];
        for (int j = 0; j < 128; ++j) o += z2[j] * rw3[j * 4 + c];
        out[g * 4 + c] = o;
    }
}

extern "C" void kernel_launch(void* const* d_in, const int* in_sizes, int n_in,
                              void* d_out, int out_size, void* d_ws, size_t ws_size,
                              hipStream_t stream) {
    const int* x          = (const int*)d_in[0];
    const int* edge_attr  = (const int*)d_in[1];
    const int* edge_index = (const int*)d_in[2];
    const int* batch      = (const int*)d_in[3];
    const float* scalars  = (const float*)d_in[4];
    const float* ne0 = (const float*)d_in[6];
    const float* ne1 = (const float*)d_in[7];
    const float* ne2 = (const float*)d_in[8];
    const float* ee0 = (const float*)d_in[9];
    const float* ee1 = (const float*)d_in[10];
    const float* Wq = (const float*)d_in[11];
    const float* bq = (const float*)d_in[12];
    const float* Wk = (const float*)d_in[13];
    const float* bk = (const float*)d_in[14];
    const float* Wv = (const float*)d_in[15];
    const float* bv = (const float*)d_in[16];
    const float* We = (const float*)d_in[17];
    const float* be = (const float*)d_in[18];
    const float* Wskip = (const float*)d_in[19];
    const float* bskip = (const float*)d_in[20];
    const float* Wbeta = (const float*)d_in[21];
    const float* ln_g = (const float*)d_in[22];
    const float* ln_b = (const float*)d_in[23];
    const float* pw1 = (const float*)d_in[24];
    const float* pb1 = (const float*)d_in[25];
    const float* pw2 = (const float*)d_in[26];
    const float* pb2 = (const float*)d_in[27];
    const float* rw1 = (const float*)d_in[28];
    const float* rb1 = (const float*)d_in[29];
    const float* rw2 = (const float*)d_in[30];
    const float* rb2 = (const float*)d_in[31];
    const float* rw3 = (const float*)d_in[32];
    const float* rb3 = (const float*)d_in[33];

    const int N = in_sizes[0] / 3;
    const int E = in_sizes[1] / 2;
    const int G = in_sizes[4] / 5;

    char* base = (char*)d_ws;
    size_t off = 0;
    auto carve = [&](size_t bytes) -> char* {
        char* p = base + off;
        off += (bytes + 255) & ~(size_t)255;
        return p;
    };
    bf16*  hbf    = (bf16*)carve((size_t)N * HID * 2);
    char*  qkvs   = (char*)carve((size_t)N * QROW);
    float* ec     = (float*)carve((size_t)32 * HID * 4);
    float* ecp4   = (float*)carve((size_t)NL * 32 * HID * 4);
    int*   ecid   = (int*)carve((size_t)E * 4);
    float* pooled = (float*)carve((size_t)G * HID * 4);
    bf16*  wcatT  = (bf16*)carve((size_t)NL * 1024 * 256 * 2);
    float* bcat   = (float*)carve((size_t)NL * 1024 * 4);
    int* counts   = (int*)carve((size_t)N * 4);
    int* fill     = (int*)carve((size_t)N * 4);
    int* incl     = (int*)carve((size_t)N * 4);
    int* bsum     = (int*)carve(4096);
    int* boff     = (int*)carve(4096);
    int* indptr   = (int*)carve((size_t)(N + 1) * 4);
    int2* sorted2 = (int2*)carve((size_t)(E + 4) * 8);   // +4 pad for unclamped pair prefetch
    // total ~120 MB

    const int* srcv = edge_index;
    const int* dstv = edge_index + E;

    zero_ws_kernel<<<(N + 255) / 256, 256, 0, stream>>>(counts, fill, N, pooled, G * HID);
    node_embed_kernel<<<(N + 3) / 4, 256, 0, stream>>>(x, ne0, ne1, ne2, hbf, N);
    ecombo_embed_kernel<<<32, 256, 0, stream>>>(ee0, ee1, ec);
    edge_prep_kernel<<<(E + 255) / 256, 256, 0, stream>>>(edge_attr, dstv, E, ecid, counts);
    {
        dim3 gp(16, 4, 4);
        pack_wcat_kernel<<<gp, 256, 0, stream>>>(Wq, Wk, Wv, Wskip, wcatT);
    }
    pack_bias_kernel<<<16, 256, 0, stream>>>(bq, bk, bv, bskip, bcat);
    combo_proj_kernel<<<NL * 32, 256, 0, stream>>>(ec, We, be, ecp4);

    int nsb = (N + 255) / 256;
    scan_local_kernel<<<nsb, 256, 0, stream>>>(counts, N, incl, bsum);
    scan_block_kernel<<<1, 256, 0, stream>>>(bsum, nsb, boff);
    scan_add_kernel<<<nsb, 256, 0, stream>>>(incl, boff, N, indptr);
    fill_sorted_kernel<<<(E + 255) / 256, 256, 0, stream>>>(dstv, srcv, ecid, indptr, E, fill, sorted2);

    for (int l = 0; l < NL; ++l) {
        dim3 g1(4, (N + 127) / 128);
        gemm_bt_kernel<<<g1, 512, 0, stream>>>(hbf, wcatT + (size_t)l * 262144,
                                               bcat + (size_t)l * 1024, qkvs, N);
        attn_node_kernel<<<(N + 3) / 4, 256, 0, stream>>>(qkvs, ecp4 + (size_t)l * 32 * HID,
                                                          indptr, sorted2,
                                                          Wbeta + (size_t)l * 768,
                                                          ln_g + (size_t)l * 256, ln_b + (size_t)l * 256,
                                                          hbf, N);
    }

    pool_kernel<<<(N + 63) / 64, 256, 0, stream>>>(hbf, batch, pooled, N);
    pragma_kernel<<<G, 256, 0, stream>>>(scalars, pw1, pb1, pw2, pb2, pooled);
    readout_kernel<<<G, 256, 0, stream>>>(pooled, rw1, rb1, rw2, rb2, rw3, rb3, (float*)d_out);
}

// Round 11
// 563.068 us; speedup vs baseline: 1.7756x; 1.1879x over previous
//
#include <hip/hip_runtime.h>
#include <hip/hip_bf16.h>

typedef short short8 __attribute__((ext_vector_type(8)));
typedef float floatx4 __attribute__((ext_vector_type(4)));
typedef float floatx2 __attribute__((ext_vector_type(2)));
typedef __hip_bfloat16 bf16;

#define HID 256
#define NL  4
#define QROW 1536   // qkvs row bytes: 512 q(bf16) | 512 skip(bf16) | 512 kv(fp8)
#define AS1 __attribute__((address_space(1)))
#define AS3 __attribute__((address_space(3)))

__device__ __forceinline__ float b2f(bf16 v) { return __bfloat162float(v); }
__device__ __forceinline__ bf16 f2b(float v) { return __float2bfloat16(v); }
__device__ __forceinline__ float us2f(unsigned short u) {
    unsigned int x = ((unsigned int)u) << 16;
    return __uint_as_float(x);
}
__device__ __forceinline__ unsigned short f2us(float v) {
    bf16 t = __float2bfloat16(v);
    return *reinterpret_cast<unsigned short*>(&t);
}

// DPP row-rotate add: sum within each 16-lane row, 4 steps, pure VALU pipe.
template <int CTRL>
__device__ __forceinline__ float row_ror_add(float x) {
    return x + __int_as_float(__builtin_amdgcn_update_dpp(
        0, __float_as_int(x), CTRL, 0xF, 0xF, true));
}

// ---------------- fused zero-init: counts, fill (N each) + pooled (G*HID) ----------------
__global__ void zero_ws_kernel(int* __restrict__ a, int* __restrict__ b, int n,
                               float* __restrict__ p, int np) {
    int i = blockIdx.x * 256 + threadIdx.x;
    if (i < n) { a[i] = 0; b[i] = 0; }
    if (i < np) p[i] = 0.f;
}

// ---------------- embeddings; float4 loads, 4 nodes/block ----------------
__global__ __launch_bounds__(256) void node_embed_kernel(const int* __restrict__ x,
                                  const float* __restrict__ e0, const float* __restrict__ e1,
                                  const float* __restrict__ e2,
                                  bf16* __restrict__ hbf, int N) {
    const int tid = threadIdx.x;
    const int n = blockIdx.x * 4 + (tid >> 6);
    if (n >= N) return;
    const int c4 = (tid & 63) * 4;
    const int i0 = x[n * 3], i1 = x[n * 3 + 1], i2 = x[n * 3 + 2];
    const float4 a = *reinterpret_cast<const float4*>(e0 + i0 * HID + c4);
    const float4 b = *reinterpret_cast<const float4*>(e1 + i1 * HID + c4);
    const float4 c = *reinterpret_cast<const float4*>(e2 + i2 * HID + c4);
    ushort4 o;
    o.x = f2us(a.x + b.x + c.x);
    o.y = f2us(a.y + b.y + c.y);
    o.z = f2us(a.z + b.z + c.z);
    o.w = f2us(a.w + b.w + c.w);
    *reinterpret_cast<ushort4*>(hbf + (size_t)n * HID + c4) = o;
}

__global__ void ecombo_embed_kernel(const float* __restrict__ e0, const float* __restrict__ e1,
                                    float* __restrict__ ec) {
    int i = blockIdx.x, c = threadIdx.x;
    ec[i * HID + c] = e0[(i >> 2) * HID + c] + e1[(i & 3) * HID + c];
}

// merged: per-edge combo id + dst histogram (one pass over edges)
__global__ void edge_prep_kernel(const int* __restrict__ ea, const int* __restrict__ dst,
                                 int E, int* __restrict__ ecid, int* __restrict__ counts) {
    int e = blockIdx.x * 256 + threadIdx.x;
    if (e < E) {
        ecid[e] = ea[e * 2] * 4 + ea[e * 2 + 1];
        atomicAdd(&counts[dst[e]], 1);
    }
}

// ALL layers at once: blockIdx.x = l*32 + i -> ecp4[l][i][c]
__global__ void combo_proj_kernel(const float* __restrict__ ec, const float* __restrict__ We,
                                  const float* __restrict__ be, float* __restrict__ ecp4) {
    __shared__ float row[HID];
    int l = blockIdx.x >> 5, i = blockIdx.x & 31, c = threadIdx.x;
    row[c] = ec[i * HID + c];
    __syncthreads();
    const float* We_l = We + (size_t)l * 65536;
    float a = be[l * 256 + c];
    for (int k = 0; k < HID; ++k) a += row[k] * We_l[k * HID + c];
    ecp4[(size_t)l * 32 * HID + i * HID + c] = a;
}

// ---------------- CSR scan ----------------
__global__ void scan_local_kernel(const int* __restrict__ counts, int N,
                                  int* __restrict__ incl, int* __restrict__ bsum) {
    __shared__ int sd[256];
    int i = threadIdx.x;
    int idx = blockIdx.x * 256 + i;
    sd[i] = (idx < N) ? counts[idx] : 0;
    __syncthreads();
    for (int off = 1; off < 256; off <<= 1) {
        int t = (i >= off) ? sd[i - off] : 0;
        __syncthreads();
        sd[i] += t;
        __syncthreads();
    }
    if (idx < N) incl[idx] = sd[i];
    if (i == 255) bsum[blockIdx.x] = sd[255];
}

__global__ void scan_block_kernel(const int* __restrict__ bsum, int nb, int* __restrict__ boff) {
    __shared__ int sd[256];
    int i = threadIdx.x;
    sd[i] = (i < nb) ? bsum[i] : 0;
    __syncthreads();
    for (int off = 1; off < 256; off <<= 1) {
        int t = (i >= off) ? sd[i - off] : 0;
        __syncthreads();
        sd[i] += t;
        __syncthreads();
    }
    if (i < nb) boff[i] = (i == 0) ? 0 : sd[i - 1];
}

__global__ void scan_add_kernel(const int* __restrict__ incl, const int* __restrict__ boff,
                                int N, int* __restrict__ indptr) {
    int idx = blockIdx.x * 256 + threadIdx.x;
    if (idx < N) indptr[idx + 1] = incl[idx] + boff[blockIdx.x];
    if (idx == 0) indptr[0] = 0;
}

// sorted2: PRE-SCALED BYTE OFFSETS (x = src*1536 qkvs row, y = ecid*1024 ecp row). +4 pad.
__global__ void fill_sorted_kernel(const int* __restrict__ dst, const int* __restrict__ srcv,
                                   const int* __restrict__ ecid, const int* __restrict__ indptr,
                                   int E, int* __restrict__ fill, int2* __restrict__ sorted2) {
    int e = blockIdx.x * 256 + threadIdx.x;
    if (e < E) {
        int d = dst[e];
        int pos = indptr[d] + atomicAdd(&fill[d], 1);
        sorted2[pos] = make_int2(srcv[e] * QROW, ecid[e] << 10);
    }
    if (e < 4) sorted2[E + e] = make_int2(0, 0);
}

// ---------------- weight packing: LDS-transposed, coalesced both sides ----------------
__global__ __launch_bounds__(256) void pack_wcat_kernel(
    const float* __restrict__ Wq, const float* __restrict__ Wk,
    const float* __restrict__ Wv, const float* __restrict__ Ws,
    bf16* __restrict__ wcatT) {
    __shared__ bf16 tile[64][65];
    const int jt = blockIdx.x;     // 0..15  (j tile of 64)
    const int kt = blockIdx.y;     // 0..3   (k tile of 64)
    const int l  = blockIdx.z;     // 0..3
    const int tid = threadIdx.x;
    const int jl = tid & 63;
    const int j = jt * 64 + jl;
    const float* W;
    int jj;
    if (j < 256)      { W = Wq; jj = j; }
    else if (j < 512) { W = Ws; jj = j - 256; }
    else {
        int g = (j - 512) >> 3, r = (j - 512) & 7;
        if (r < 4) { W = Wk; jj = 4 * g + r; }
        else       { W = Wv; jj = 4 * g + r - 4; }
    }
    const float* Wbase = W + (size_t)l * 65536 + jj + (size_t)(kt * 64) * 256;
    const int kr = tid >> 6;       // 0..3
#pragma unroll
    for (int i = 0; i < 16; ++i) {
        const int kl = kr + i * 4;
        tile[kl][jl] = f2b(Wbase[(size_t)kl * 256]);
    }
    __syncthreads();
    const int kl2 = tid & 63;
    const int jr = tid >> 6;
    bf16* out = wcatT + (size_t)l * 262144 + (size_t)(jt * 64) * 256 + kt * 64 + kl2;
#pragma unroll
    for (int i = 0; i < 16; ++i) {
        const int jl2 = jr + i * 4;
        out[(size_t)jl2 * 256] = tile[kl2][jl2];
    }
}

__global__ void pack_bias_kernel(const float* __restrict__ bq, const float* __restrict__ bk,
                                 const float* __restrict__ bv, const float* __restrict__ bs,
                                 float* __restrict__ bcat) {
    int idx = blockIdx.x * 256 + threadIdx.x;      // < 4096
    if (idx < 4096) {
        int l = idx >> 10, j = idx & 1023;
        const float* B;
        int jj;
        if (j < 256)      { B = bq; jj = j; }
        else if (j < 512) { B = bs; jj = j - 256; }
        else {
            int g = (j - 512) >> 3, r = (j - 512) & 7;
            if (r < 4) { B = bk; jj = 4 * g + r; }
            else       { B = bv; jj = 4 * g + r - 4; }
        }
        bcat[idx] = B[l * 256 + jj];
    }
}

// ---------------- double-buffered MFMA GEMM (R31) ----------------
// R30 counters: gemm 67us with MfmaUtil 14%, Occ 17%, 1.9TB/s on 129MB -- the stage->drain->
// compute serialization (drain BEFORE compute) left load latency unhidden. R31: BM=128 BN=128,
// 256 thr (4 waves, 64x64 each), TWO 32KB LDS buffers (64KB -> 2 blocks/CU). Per K-step:
// issue stage(t+1 -> other buf) FIRST, compute buf t, THEN __syncthreads() -- the compiler's
// vmcnt(0) drain now lands after ~1500cy of MFMA, hiding the prefetch. 5 barriers vs 8.
// Grid 64*q with XCD-private m-ranges (k=d&7, mt=k*q+(j>>3), col=j&7, bijective): the 8
// col-blocks of an m-tile run adjacently on ONE XCD -> A fetched ~once (25.6MB). Staging
// swizzle (jsw) / read (phys) / fp8-kv epilogue verbatim from proven gemm_bt.
__global__ __launch_bounds__(256, 2) void gemm_db_kernel(
    const bf16* __restrict__ A, const bf16* __restrict__ BT,
    const float* __restrict__ bias, char* __restrict__ Cb, int M) {
    __shared__ __align__(16) bf16 smem[32768];   // 64KB: [sA0|sB0|sA1|sB1] of 8192 elems each
    const int tid = threadIdx.x;
    const int lane = tid & 63;
    const int wave = tid >> 6;
    const int mtiles = (M + 127) >> 7;
    const int q = (mtiles + 7) >> 3;
    const int d = blockIdx.x;
    const int xcd = d & 7;
    const int j = d >> 3;
    const int mt = xcd * q + (j >> 3);
    if (mt >= mtiles) return;                    // block-uniform: safe before barriers
    const int m0 = mt << 7;
    const int n0 = (j & 7) << 7;
    const int fr = lane & 15;
    const int quad = lane >> 4;
    const int sub = lane >> 3;
    const int slot = lane & 7;
    const int jsw = slot ^ sub;
    const int wm = (wave >> 1) * 64;
    const int wn = (wave & 1) * 64;
    const bool isfp8 = (n0 >= 512);

    bf16* sA0 = smem;          bf16* sB0 = smem + 8192;
    bf16* sA1 = smem + 16384;  bf16* sB1 = smem + 24576;

    auto stage = [&](int kc, bf16* sA, bf16* sB) {
#pragma unroll
        for (int p = 0; p < 4; ++p) {
            const int brow = (wave * 4 + p) * 8;
            const int gm = min(m0 + brow + sub, M - 1);
            __builtin_amdgcn_global_load_lds(
                (const AS1 void*)(A + (size_t)gm * 256 + kc + jsw * 8),
                (AS3 void*)(sA + brow * 64), 16, 0, 0);
            __builtin_amdgcn_global_load_lds(
                (const AS1 void*)(BT + (size_t)(n0 + brow + sub) * 256 + kc + jsw * 8),
                (AS3 void*)(sB + brow * 64), 16, 0, 0);
        }
    };

    floatx4 acc[4][4] = {};
    stage(0, sA0, sB0);
    __syncthreads();
#pragma unroll
    for (int t = 0; t < 4; ++t) {
        bf16* cA = (t & 1) ? sA1 : sA0;
        bf16* cB = (t & 1) ? sB1 : sB0;
        if (t < 3) stage((t + 1) * 64, (t & 1) ? sA0 : sA1, (t & 1) ? sB0 : sB1);
#pragma unroll
        for (int ks = 0; ks < 64; ks += 32) {
            const int ch = (ks >> 3) + quad;
            const int phys = (ch ^ (fr & 7)) << 3;
            short8 af[4], bfm[4];
#pragma unroll
            for (int i = 0; i < 4; ++i) {
                af[i]  = *reinterpret_cast<const short8*>(&cA[(wm + i * 16 + fr) * 64 + phys]);
                bfm[i] = *reinterpret_cast<const short8*>(&cB[(wn + i * 16 + fr) * 64 + phys]);
            }
#pragma unroll
            for (int mi = 0; mi < 4; ++mi)
#pragma unroll
                for (int ni = 0; ni < 4; ++ni)
                    acc[mi][ni] = __builtin_amdgcn_mfma_f32_16x16x32_bf16(af[mi], bfm[ni], acc[mi][ni], 0, 0, 0);
        }
        __syncthreads();   // drains the t+1 stage AFTER compute -> latency hidden
    }

    // epilogue: smem round-trip (CSTR=136), wide stores; fp8 kv conversion (block-uniform)
    float bias4[4];
#pragma unroll
    for (int ni = 0; ni < 4; ++ni) bias4[ni] = bias[n0 + wn + ni * 16 + fr];
    constexpr int CSTR = 136;
    bf16* sC = smem;   // 128*136*2B = 34.8KB <= 64KB; prior reads all consumed (post-barrier)
#pragma unroll
    for (int mi = 0; mi < 4; ++mi)
#pragma unroll
        for (int ni = 0; ni < 4; ++ni)
#pragma unroll
            for (int r = 0; r < 4; ++r)
                sC[(wm + mi * 16 + quad * 4 + r) * CSTR + wn + ni * 16 + fr] =
                    f2b(acc[mi][ni][r] + bias4[ni]);
    __syncthreads();
#pragma unroll
    for (int p = 0; p < 8; ++p) {
        const int ci = tid + p * 256;
        const int row = ci >> 4;
        const int c8 = (ci & 15) << 3;
        if (m0 + row < M) {
            const uint4 vv = *reinterpret_cast<const uint4*>(&sC[row * CSTR + c8]);
            char* crow = Cb + (size_t)(m0 + row) * QROW;
            const int col = n0 + c8;
            if (!isfp8) {
                *reinterpret_cast<uint4*>(crow + col * 2) = vv;
            } else {
                const float f0 = us2f((unsigned short)(vv.x & 0xffff)), f1 = us2f((unsigned short)(vv.x >> 16));
                const float f2 = us2f((unsigned short)(vv.y & 0xffff)), f3 = us2f((unsigned short)(vv.y >> 16));
                const float f4 = us2f((unsigned short)(vv.z & 0xffff)), f5 = us2f((unsigned short)(vv.z >> 16));
                const float f6 = us2f((unsigned short)(vv.w & 0xffff)), f7 = us2f((unsigned short)(vv.w >> 16));
                int lo = 0, hi = 0;
                lo = __builtin_amdgcn_cvt_pk_fp8_f32(f0, f1, lo, false);
                lo = __builtin_amdgcn_cvt_pk_fp8_f32(f2, f3, lo, true);
                hi = __builtin_amdgcn_cvt_pk_fp8_f32(f4, f5, hi, false);
                hi = __builtin_amdgcn_cvt_pk_fp8_f32(f6, f7, hi, true);
                uint2 o;
                o.x = (unsigned)lo;
                o.y = (unsigned)hi;
                *reinterpret_cast<uint2*>(crow + 1024 + (col - 512)) = o;
            }
        }
    }
}

// ---------------- fused attention: wave-per-node, fp8 kv gather (R27/R30-proven) ----------------
__global__ __launch_bounds__(256) void attn_node_kernel(
    const char* __restrict__ qkvs,     // [N,1536B] q bf16 | skip bf16 | kv fp8 interleaved
    const float* __restrict__ ecp,     // [32,256] this layer
    const int* __restrict__ indptr, const int2* __restrict__ sorted2,
    const float* __restrict__ Wbeta_l, const float* __restrict__ lng, const float* __restrict__ lnb,
    bf16* __restrict__ hbf, int N) {
    const int tid = threadIdx.x;
    const int wv = tid >> 6;
    const int lane = tid & 63;
    const int n = blockIdx.x * 4 + wv;
    if (n >= N) return;
    const int c0 = lane * 4;
    const ushort4 qu = *reinterpret_cast<const ushort4*>(qkvs + (size_t)n * QROW + lane * 8);
    const float q0 = us2f(qu.x), q1 = us2f(qu.y), q2 = us2f(qu.z), q3 = us2f(qu.w);
    float a0 = 0.f, a1 = 0.f, a2 = 0.f, a3 = 0.f, wsum = 0.f;
    const int e0 = indptr[n], e1 = indptr[n + 1];
    const char* __restrict__ kvb = qkvs + 1024 + lane * 8;   // + src*1536 per edge
    const char* __restrict__ epb = (const char*)ecp + c0 * 4;

    auto edge_body = [&](const uint2& kv, const float4& ep) {
        const floatx2 ka = __builtin_amdgcn_cvt_pk_f32_fp8(kv.x, false);
        const floatx2 kb = __builtin_amdgcn_cvt_pk_f32_fp8(kv.x, true);
        const floatx2 va = __builtin_amdgcn_cvt_pk_f32_fp8(kv.y, false);
        const floatx2 vb = __builtin_amdgcn_cvt_pk_f32_fp8(kv.y, true);
        float t = q0 * (ka.x + ep.x) + q1 * (ka.y + ep.y) + q2 * (kb.x + ep.z) + q3 * (kb.y + ep.w);
        t = row_ror_add<0x121>(t);
        t = row_ror_add<0x122>(t);
        t = row_ror_add<0x124>(t);
        t = row_ror_add<0x128>(t);
        const float w = __expf(t * 0.125f);
        a0 += w * (va.x + ep.x);
        a1 += w * (va.y + ep.y);
        a2 += w * (vb.x + ep.z);
        a3 += w * (vb.y + ep.w);
        wsum += w;
    };

    if (e0 < e1) {
        int2 m0 = sorted2[e0];
        int2 m1 = sorted2[e0 + 1];                 // pad makes this safe
        uint2 kv0 = *reinterpret_cast<const uint2*>(kvb + (unsigned)m0.x);
        uint2 kv1 = *reinterpret_cast<const uint2*>(kvb + (unsigned)m1.x);
        int ee = e0;
        for (; ee + 1 < e1; ee += 2) {
            const int2 mN0 = sorted2[ee + 2];
            const int2 mN1 = sorted2[ee + 3];
            const uint2 kvN0 = *reinterpret_cast<const uint2*>(kvb + (unsigned)mN0.x);
            const uint2 kvN1 = *reinterpret_cast<const uint2*>(kvb + (unsigned)mN1.x);
            const float4 ep0 = *reinterpret_cast<const float4*>(epb + (unsigned)m0.y);
            const float4 ep1 = *reinterpret_cast<const float4*>(epb + (unsigned)m1.y);
            edge_body(kv0, ep0);
            edge_body(kv1, ep1);
            m0 = mN0; m1 = mN1;
            kv0 = kvN0; kv1 = kvN1;
        }
        if (ee < e1) {                             // odd degree: slot0 holds edge ee
            const float4 ep0 = *reinterpret_cast<const float4*>(epb + (unsigned)m0.y);
            edge_body(kv0, ep0);
        }
    }
    const float inv = (wsum > 0.f) ? 1.f / wsum : 0.f;
    const float o0 = a0 * inv, o1 = a1 * inv, o2 = a2 * inv, o3 = a3 * inv;
    const ushort4 ru = *reinterpret_cast<const ushort4*>(qkvs + (size_t)n * QROW + 512 + lane * 8);
    const float r0 = us2f(ru.x), r1 = us2f(ru.y), r2 = us2f(ru.z), r3 = us2f(ru.w);
    const float4 w1 = *reinterpret_cast<const float4*>(Wbeta_l + c0);
    const float4 w2 = *reinterpret_cast<const float4*>(Wbeta_l + 256 + c0);
    const float4 w3 = *reinterpret_cast<const float4*>(Wbeta_l + 512 + c0);
    float tb = o0 * w1.x + o1 * w1.y + o2 * w1.z + o3 * w1.w
             + r0 * w2.x + r1 * w2.y + r2 * w2.z + r3 * w2.w
             + (o0 - r0) * w3.x + (o1 - r1) * w3.y + (o2 - r2) * w3.z + (o3 - r3) * w3.w;
#pragma unroll
    for (int off = 32; off > 0; off >>= 1) tb += __shfl_xor(tb, off);
    const float beta = 1.f / (1.f + __expf(-tb));
    float g0 = fmaxf(beta * r0 + (1.f - beta) * o0, 0.f);
    float g1 = fmaxf(beta * r1 + (1.f - beta) * o1, 0.f);
    float g2 = fmaxf(beta * r2 + (1.f - beta) * o2, 0.f);
    float g3 = fmaxf(beta * r3 + (1.f - beta) * o3, 0.f);
    float s1 = g0 + g1 + g2 + g3;
    float s2 = g0 * g0 + g1 * g1 + g2 * g2 + g3 * g3;
#pragma unroll
    for (int off = 32; off > 0; off >>= 1) { s1 += __shfl_xor(s1, off); s2 += __shfl_xor(s2, off); }
    const float mu = s1 * (1.f / 256.f);
    const float var = s2 * (1.f / 256.f) - mu * mu;
    const float rish = rsqrtf(fmaxf(var, 0.f) + 1e-5f);
    const float4 gg = *reinterpret_cast<const float4*>(lng + c0);
    const float4 bb = *reinterpret_cast<const float4*>(lnb + c0);
    ushort4 hb = *reinterpret_cast<ushort4*>(hbf + (size_t)n * HID + c0);
    float h0 = us2f(hb.x) + (g0 - mu) * rish * gg.x + bb.x;
    float h1 = us2f(hb.y) + (g1 - mu) * rish * gg.y + bb.y;
    float h2 = us2f(hb.z) + (g2 - mu) * rish * gg.z + bb.z;
    float h3 = us2f(hb.w) + (g3 - mu) * rish * gg.w + bb.w;
    hb.x = f2us(h0); hb.y = f2us(h1); hb.z = f2us(h2); hb.w = f2us(h3);
    *reinterpret_cast<ushort4*>(hbf + (size_t)n * HID + c0) = hb;
}

// ---------------- hierarchical pooling (reads bf16 h) ----------------
__global__ __launch_bounds__(256) void pool_kernel(const bf16* __restrict__ hbf,
                                                   const int* __restrict__ batch,
                                                   float* __restrict__ pooled, int N) {
    __shared__ int sb[64];
    const int c = threadIdx.x;
    const int n0 = blockIdx.x * 64;
    const int cnt = min(64, N - n0);
    if (c < 64 && c < cnt) sb[c] = batch[n0 + c];
    __syncthreads();
    float acc = 0.f;
    int gcur = sb[0];
    for (int i = 0; i < cnt; ++i) {
        const int g = sb[i];
        if (g != gcur) {
            atomicAdd(&pooled[(size_t)gcur * HID + c], acc);
            acc = 0.f;
            gcur = g;
        }
        acc += b2f(hbf[(size_t)(n0 + i) * HID + c]);
    }
    atomicAdd(&pooled[(size_t)gcur * HID + c], acc);
}

__global__ void pragma_kernel(const float* __restrict__ scalars,
                              const float* __restrict__ pw1, const float* __restrict__ pb1,
                              const float* __restrict__ pw2, const float* __restrict__ pb2,
                              float* __restrict__ pooled) {
    int g = blockIdx.x, c = threadIdx.x;
    __shared__ float s5[5];
    __shared__ float t1[256];
    if (c < 5) s5[c] = scalars[g * 5 + c];
    __syncthreads();
    float a = pb1[c];
    for (int k = 0; k < 5; ++k) a += s5[k] * pw1[k * 256 + c];
    t1[c] = fmaxf(a, 0.f);
    __syncthreads();
    float p = pb2[c];
    for (int j = 0; j < 256; ++j) p += t1[j] * pw2[j * 256 + c];
    pooled[g * 256 + c] += p;
}

__global__ void readout_kernel(const float* __restrict__ pooled,
                               const float* __restrict__ rw1, const float* __restrict__ rb1,
                               const float* __restrict__ rw2, const float* __restrict__ rb2,
                               const float* __restrict__ rw3, const float* __restrict__ rb3,
                               float* __restrict__ out) {
    int g = blockIdx.x, c = threadIdx.x;
    __shared__ float pl[256], z1[256], z2[128];
    pl[c] = pooled[g * 256 + c];
    __syncthreads();
    float z = rb1[c];
    for (int k = 0; k < 256; ++k) z += pl[k] * rw1[k * 256 + c];
    z1[c] = fmaxf(z, 0.f);
    __syncthreads();
    if (c < 128) {
        float v = rb2[c];
        for (int j = 0; j < 256; ++j) v += z1[j] * rw2[j * 128 + c];
        z2[c] = fmaxf(v, 0.f);
    }
    __syncthreads();
    if (c < 4) {
        float o = rb3[c];
        for (int j = 0; j < 128; ++j) o += z2[j] * rw3[j * 4 + c];
        out[g * 4 + c] = o;
    }
}

extern "C" void kernel_launch(void* const* d_in, const int* in_sizes, int n_in,
                              void* d_out, int out_size, void* d_ws, size_t ws_size,
                              hipStream_t stream) {
    const int* x          = (const int*)d_in[0];
    const int* edge_attr  = (const int*)d_in[1];
    const int* edge_index = (const int*)d_in[2];
    const int* batch      = (const int*)d_in[3];
    const float* scalars  = (const float*)d_in[4];
    const float* ne0 = (const float*)d_in[6];
    const float* ne1 = (const float*)d_in[7];
    const float* ne2 = (const float*)d_in[8];
    const float* ee0 = (const float*)d_in[9];
    const float* ee1 = (const float*)d_in[10];
    const float* Wq = (const float*)d_in[11];
    const float* bq = (const float*)d_in[12];
    const float* Wk = (const float*)d_in[13];
    const float* bk = (const float*)d_in[14];
    const float* Wv = (const float*)d_in[15];
    const float* bv = (const float*)d_in[16];
    const float* We = (const float*)d_in[17];
    const float* be = (const float*)d_in[18];
    const float* Wskip = (const float*)d_in[19];
    const float* bskip = (const float*)d_in[20];
    const float* Wbeta = (const float*)d_in[21];
    const float* ln_g = (const float*)d_in[22];
    const float* ln_b = (const float*)d_in[23];
    const float* pw1 = (const float*)d_in[24];
    const float* pb1 = (const float*)d_in[25];
    const float* pw2 = (const float*)d_in[26];
    const float* pb2 = (const float*)d_in[27];
    const float* rw1 = (const float*)d_in[28];
    const float* rb1 = (const float*)d_in[29];
    const float* rw2 = (const float*)d_in[30];
    const float* rb2 = (const float*)d_in[31];
    const float* rw3 = (const float*)d_in[32];
    const float* rb3 = (const float*)d_in[33];

    const int N = in_sizes[0] / 3;
    const int E = in_sizes[1] / 2;
    const int G = in_sizes[4] / 5;

    char* base = (char*)d_ws;
    size_t off = 0;
    auto carve = [&](size_t bytes) -> char* {
        char* p = base + off;
        off += (bytes + 255) & ~(size_t)255;
        return p;
    };
    bf16*  hbf    = (bf16*)carve((size_t)N * HID * 2);
    char*  qkvs   = (char*)carve((size_t)N * QROW);
    float* ec     = (float*)carve((size_t)32 * HID * 4);
    float* ecp4   = (float*)carve((size_t)NL * 32 * HID * 4);
    int*   ecid   = (int*)carve((size_t)E * 4);
    float* pooled = (float*)carve((size_t)G * HID * 4);
    bf16*  wcatT  = (bf16*)carve((size_t)NL * 1024 * 256 * 2);
    float* bcat   = (float*)carve((size_t)NL * 1024 * 4);
    int* counts   = (int*)carve((size_t)N * 4);
    int* fill     = (int*)carve((size_t)N * 4);
    int* incl     = (int*)carve((size_t)N * 4);
    int* bsum     = (int*)carve(4096);
    int* boff     = (int*)carve(4096);
    int* indptr   = (int*)carve((size_t)(N + 1) * 4);
    int2* sorted2 = (int2*)carve((size_t)(E + 4) * 8);   // +4 pad for unclamped pair prefetch
    // total ~120 MB

    const int* srcv = edge_index;
    const int* dstv = edge_index + E;

    zero_ws_kernel<<<(N + 255) / 256, 256, 0, stream>>>(counts, fill, N, pooled, G * HID);
    node_embed_kernel<<<(N + 3) / 4, 256, 0, stream>>>(x, ne0, ne1, ne2, hbf, N);
    ecombo_embed_kernel<<<32, 256, 0, stream>>>(ee0, ee1, ec);
    edge_prep_kernel<<<(E + 255) / 256, 256, 0, stream>>>(edge_attr, dstv, E, ecid, counts);
    {
        dim3 gp(16, 4, 4);
        pack_wcat_kernel<<<gp, 256, 0, stream>>>(Wq, Wk, Wv, Wskip, wcatT);
    }
    pack_bias_kernel<<<16, 256, 0, stream>>>(bq, bk, bv, bskip, bcat);
    combo_proj_kernel<<<NL * 32, 256, 0, stream>>>(ec, We, be, ecp4);

    int nsb = (N + 255) / 256;
    scan_local_kernel<<<nsb, 256, 0, stream>>>(counts, N, incl, bsum);
    scan_block_kernel<<<1, 256, 0, stream>>>(bsum, nsb, boff);
    scan_add_kernel<<<nsb, 256, 0, stream>>>(incl, boff, N, indptr);
    fill_sorted_kernel<<<(E + 255) / 256, 256, 0, stream>>>(dstv, srcv, ecid, indptr, E, fill, sorted2);

    const int mtiles = (N + 127) / 128;
    const int qx = (mtiles + 7) / 8;
    const int gemm_grid = 64 * qx;   // 8 XCD groups x qx m-slots x 8 col-tiles

    for (int l = 0; l < NL; ++l) {
        gemm_db_kernel<<<gemm_grid, 256, 0, stream>>>(hbf, wcatT + (size_t)l * 262144,
                                                      bcat + (size_t)l * 1024, qkvs, N);
        attn_node_kernel<<<(N + 3) / 4, 256, 0, stream>>>(qkvs, ecp4 + (size_t)l * 32 * HID,
                                                          indptr, sorted2,
                                                          Wbeta + (size_t)l * 768,
                                                          ln_g + (size_t)l * 256, ln_b + (size_t)l * 256,
                                                          hbf, N);
    }

    pool_kernel<<<(N + 63) / 64, 256, 0, stream>>>(hbf, batch, pooled, N);
    pragma_kernel<<<G, 256, 0, stream>>>(scalars, pw1, pb1, pw2, pb2, pooled);
    readout_kernel<<<G, 256, 0, stream>>>(pooled, rw1, rb1, rw2, rb2, rw3, rb3, (float*)d_out);
}